// Round 17
// baseline (157.664 us; speedup 1.0000x reference)
//
#include <hip/hip_runtime.h>
#include <hip/hip_fp16.h>

// HyenaFilter = implicit-filter MLP (tiny) + FFT convolution.
// fftconv (fft_size=16384 >= 2L) == causal linear conv; bias folded into k[0].
// R16: 157.6us (conv 73, VALU 56% + LDS ~40% => jointly saturated).
// R17: packed FP32 — CDNA4's 157TF fp32 peak includes 2x from v_pk_*_f32;
//   scalar code gets half. Butterflies rewritten on ext_vector_type(2) float
//   so <2 x float> adds/fmas lower to v_pk_add/fma_f32. Twiddle mult via
//   x*(c-is) = c*x + s*(x.yx*{1,-1}); -i*v / +i*v as swizzle+negate.

#define DIMC  768
#define BANDS 16
#define FO    64
#define LSEQ  8192
#define NF    16384
#define PI_F  3.14159265358979323846f
#define RSQ2  0.70710678118654752f

typedef float v2f __attribute__((ext_vector_type(2)));

#define REP32(M) M(0) M(1) M(2) M(3) M(4) M(5) M(6) M(7) M(8) M(9) M(10) M(11) \
    M(12) M(13) M(14) M(15) M(16) M(17) M(18) M(19) M(20) M(21) M(22) M(23) \
    M(24) M(25) M(26) M(27) M(28) M(29) M(30) M(31)

__device__ __forceinline__ int swz(int i) { return i ^ ((i >> 4) & 15); }

__device__ __forceinline__ v2f mni(v2f v) { v2f t = v.yx; t.y = -t.y; return t; } // -i*v
__device__ __forceinline__ v2f pli(v2f v) { v2f t = v.yx; t.x = -t.x; return t; } // +i*v
__device__ __forceinline__ v2f cmulm(v2f x, float c, float s) {   // x*(c - i s)
    v2f t = x.yx; t.y = -t.y;            // (xi, -xr)
    return x * c + t * s;                // pk_fma
}
__device__ __forceinline__ v2f cmulp(v2f x, float c, float s) {   // x*(c + i s)
    v2f t = x.yx; t.x = -t.x;            // (-xi, xr)
    return x * c + t * s;
}

#define TWCHAIN7(TH) \
    float c1=__cosf(TH), s1=__sinf(TH); \
    float c2=c1*c1-s1*s1, s2=2.f*c1*s1; \
    float c3=c1*c2-s1*s2, s3=s1*c2+c1*s2; \
    float c4=c2*c2-s2*s2, s4=2.f*c2*s2; \
    float c5=c2*c3-s2*s3, s5=s2*c3+c2*s3; \
    float c6=c3*c3-s3*s3, s6=2.f*c3*s3; \
    float c7=c3*c4-s3*s4, s7=s3*c4+c3*s4

// ---- full forward radix-8 DIF stage (packed) ------------------------------
template<int SH>
__device__ __forceinline__ void fwd8_stage(v2f* L, int t)
{
    __syncthreads();
    const int S = 1 << SH;
#pragma unroll 1
    for (int m = 0; m < 2; ++m) {
        int b = t + (m << 10);
        int q = b & (S - 1);
        int p = ((b >> SH) << (SH + 3)) + q;
        v2f u0 = L[swz(p)];
        v2f u1 = L[swz(p + S)];
        v2f u2 = L[swz(p + 2 * S)];
        v2f u3 = L[swz(p + 3 * S)];
        v2f u4 = L[swz(p + 4 * S)];
        v2f u5 = L[swz(p + 5 * S)];
        v2f u6 = L[swz(p + 6 * S)];
        v2f u7 = L[swz(p + 7 * S)];
        v2f a0 = u0 + u4, b0 = u0 - u4;
        v2f a1 = u1 + u5, b1 = u1 - u5;
        v2f a2 = u2 + u6, b2 = u2 - u6;
        v2f a3 = u3 + u7, b3 = u3 - u7;
        v2f e0 = a0 + a2, e1 = a0 - a2;
        v2f f0 = a1 + a3, f1 = a1 - a3;
        v2f y0 = e0 + f0, y4 = e0 - f0;
        v2f nf1 = mni(f1);
        v2f y2 = e1 + nf1, y6 = e1 - nf1;
        v2f v1 = cmulm(b1,  RSQ2, RSQ2);
        v2f v2 = mni(b2);
        v2f v3 = cmulm(b3, -RSQ2, RSQ2);
        v2f g0 = b0 + v2, g1 = b0 - v2;
        v2f h0 = v1 + v3, h1 = v1 - v3;
        v2f y1 = g0 + h0, y5 = g0 - h0;
        v2f nh1 = mni(h1);
        v2f y3 = g1 + nh1, y7 = g1 - nh1;
        float th = (float)q * (PI_F / (4.0f * (float)S));
        TWCHAIN7(th);
        L[swz(p)]         = y0;
        L[swz(p + S)]     = cmulm(y1, c1, s1);
        L[swz(p + 2 * S)] = cmulm(y2, c2, s2);
        L[swz(p + 3 * S)] = cmulm(y3, c3, s3);
        L[swz(p + 4 * S)] = cmulm(y4, c4, s4);
        L[swz(p + 5 * S)] = cmulm(y5, c5, s5);
        L[swz(p + 6 * S)] = cmulm(y6, c6, s6);
        L[swz(p + 7 * S)] = cmulm(y7, c7, s7);
    }
}

// first fwd stage (S=2048), zero-padded input: u4..u7 = 0
__device__ __forceinline__ void fwd8_first(v2f* L, int q,
                                           v2f u0, v2f u1, v2f u2, v2f u3)
{
    v2f e0 = u0 + u2, e1 = u0 - u2;
    v2f f0 = u1 + u3, f1 = u1 - u3;
    v2f y0 = e0 + f0, y4 = e0 - f0;
    v2f nf1 = mni(f1);
    v2f y2 = e1 + nf1, y6 = e1 - nf1;
    v2f v1 = cmulm(u1,  RSQ2, RSQ2);
    v2f v2 = mni(u2);
    v2f v3 = cmulm(u3, -RSQ2, RSQ2);
    v2f g0 = u0 + v2, g1 = u0 - v2;
    v2f h0 = v1 + v3, h1 = v1 - v3;
    v2f y1 = g0 + h0, y5 = g0 - h0;
    v2f nh1 = mni(h1);
    v2f y3 = g1 + nh1, y7 = g1 - nh1;
    float th = (float)q * (PI_F / 8192.0f);
    TWCHAIN7(th);
    L[swz(q)]         = y0;
    L[swz(q + 2048)]  = cmulm(y1, c1, s1);
    L[swz(q + 4096)]  = cmulm(y2, c2, s2);
    L[swz(q + 6144)]  = cmulm(y3, c3, s3);
    L[swz(q + 8192)]  = cmulm(y4, c4, s4);
    L[swz(q + 10240)] = cmulm(y5, c5, s5);
    L[swz(q + 12288)] = cmulm(y6, c6, s6);
    L[swz(q + 14336)] = cmulm(y7, c7, s7);
}

// ---- inverse radix-8 DIT stage (packed) -----------------------------------
template<int SH>
__device__ __forceinline__ void inv8_stage(v2f* L, int t)
{
    __syncthreads();
    const int S = 1 << SH;
#pragma unroll 1
    for (int m = 0; m < 2; ++m) {
        int b = t + (m << 10);
        int q = b & (S - 1);
        int p = ((b >> SH) << (SH + 3)) + q;
        float th = (float)q * (PI_F / (4.0f * (float)S));
        TWCHAIN7(th);
        v2f y0 = L[swz(p)];
        v2f y1 = cmulp(L[swz(p + S)],     c1, s1);
        v2f y2 = cmulp(L[swz(p + 2*S)],   c2, s2);
        v2f y3 = cmulp(L[swz(p + 3*S)],   c3, s3);
        v2f y4 = cmulp(L[swz(p + 4*S)],   c4, s4);
        v2f y5 = cmulp(L[swz(p + 5*S)],   c5, s5);
        v2f y6 = cmulp(L[swz(p + 6*S)],   c6, s6);
        v2f y7 = cmulp(L[swz(p + 7*S)],   c7, s7);
        v2f E0 = y0 + y4, F0 = y0 - y4;
        v2f E1 = y2 + y6, F1 = pli(y2 - y6);
        v2f a0 = E0 + E1, a2 = E0 - E1;
        v2f a1 = F0 + F1, a3 = F0 - F1;
        v2f G0 = y1 + y5, H0 = y1 - y5;
        v2f G1 = y3 + y7, H1 = pli(y3 - y7);
        v2f w0 = G0 + G1, w2 = G0 - G1;
        v2f w1 = H0 + H1, w3 = H0 - H1;
        v2f b0 = w0;
        v2f b1 = cmulp(w1,  RSQ2, RSQ2);
        v2f b2 = pli(w2);
        v2f b3 = cmulp(w3, -RSQ2, RSQ2);
        L[swz(p)]         = a0 + b0;
        L[swz(p + S)]     = a1 + b1;
        L[swz(p + 2 * S)] = a2 + b2;
        L[swz(p + 3 * S)] = a3 + b3;
        L[swz(p + 4 * S)] = a0 - b0;
        L[swz(p + 5 * S)] = a1 - b1;
        L[swz(p + 6 * S)] = a2 - b2;
        L[swz(p + 7 * S)] = a3 - b3;
    }
}

// trivial-twiddle radix-4 (S=1) fwd / inv (packed)
__device__ __forceinline__ void bf4f0(v2f& a, v2f& b, v2f& c, v2f& d)
{
    v2f A = a + c, B = a - c, C = b + d, D = mni(b - d);
    a = A + C; b = B + D; c = A - C; d = B - D;
}
__device__ __forceinline__ void bf4i0(v2f& a, v2f& b, v2f& c, v2f& d)
{
    v2f e0 = a + c, e1 = a - c, f0 = b + d, f1 = pli(b - d);
    a = e0 + f0; b = e1 + f1; c = e0 - f0; d = e1 - f1;
}

// ---------- Kernel 1: MLP hidden states h2[FO][LSEQ] ----------------------
__global__ void hidden_kernel(const float* __restrict__ W0, const float* __restrict__ b0,
                              const float* __restrict__ W1, const float* __restrict__ b1,
                              const float* __restrict__ W2, const float* __restrict__ b2,
                              const float* __restrict__ freq, float* __restrict__ hws)
{
    const int lane = threadIdx.x & 63;
    const int p = blockIdx.x * (blockDim.x >> 6) + (threadIdx.x >> 6);
    if (p >= LSEQ) return;
    const float tt = (float)p / (float)(LSEQ - 1);
    const float w  = 6.283185307179586f * (float)p / (float)LSEQ;

    float acc = b0[lane] + tt * W0[lane];
#pragma unroll
    for (int j = 0; j < BANDS; ++j) {
        float f = 1e-4f + (float)j * ((15.0f - 1e-4f) / 15.0f);
        float a = f * w;
        acc += __cosf(a)  * W0[(1 + j) * FO + lane];
        acc += -__sinf(a) * W0[(1 + BANDS + j) * FO + lane];
    }
    float h = __sinf(freq[lane] * acc);

    acc = b1[lane];
#pragma unroll
    for (int e = 0; e < FO; ++e) acc += __shfl(h, e) * W1[e * FO + lane];
    float h1 = __sinf(freq[lane] * acc);

    acc = b2[lane];
#pragma unroll
    for (int e = 0; e < FO; ++e) acc += __shfl(h1, e) * W2[e * FO + lane];
    float h2 = __sinf(freq[lane] * acc);

    hws[lane * LSEQ + p] = h2;
}

// ---------- Kernel 2: k[d][p] = (h2 . Wf) * (exp(-t|delta|)+0.05) ---------
#define DCHUNK 96
__global__ __launch_bounds__(256)
void filter_kernel(const float* __restrict__ hws, const float* __restrict__ Wf,
                   float* __restrict__ kws)
{
    __shared__ float hsh[FO][257];
    const int tid = threadIdx.x;
    const int p  = blockIdx.x * 256 + tid;
    const int d0 = blockIdx.y * DCHUNK;
#pragma unroll 1
    for (int j = 0; j < FO; ++j) hsh[j][tid] = hws[j * LSEQ + p];
    __syncthreads();
    const float tt = (float)p / (float)(LSEQ - 1);
    const float min_decay = -3.0701134573253937f;
    const float max_decay = -15.350567286626971f;
#pragma unroll 1
    for (int c = 0; c < DCHUNK / 32; ++c) {
        const int dc = d0 + c * 32;
#define DEFA(I) float a##I = 0.f;
        REP32(DEFA)
#undef DEFA
#pragma unroll 4
        for (int j = 0; j < FO; ++j) {
            float hj = hsh[j][tid];
            const float* Wj = Wf + j * DIMC + dc;
#define FMA_(I) a##I = fmaf(hj, Wj[I], a##I);
            REP32(FMA_)
#undef FMA_
        }
#define ST_(I) { int d = dc + I; \
    float delta = min_decay + (max_decay - min_decay) * ((float)d / (float)(DIMC - 1)); \
    float dec = __expf(-tt * fabsf(delta)); \
    kws[(size_t)d * LSEQ + p] = a##I * (dec + 0.05f); }
        REP32(ST_)
#undef ST_
    }
}

// ---------- Kernel 3: K-hat for TWO real channels per complex FFT ---------
template<int MODE>
__global__ __launch_bounds__(1024)
void kfft_kernel(const float* __restrict__ kf, const float* __restrict__ bias,
                 __half2* __restrict__ KF, float* __restrict__ outbase)
{
    __shared__ v2f L[NF];
    const int g = blockIdx.x, t = threadIdx.x;
    const int da = 2 * g, db = 2 * g + 1;
    const float* ka = kf + (size_t)da * LSEQ;
    const float* kb = kf + (size_t)db * LSEQ;
#pragma unroll 1
    for (int m = 0; m < 2; ++m) {
        int q = t + (m << 10);
        float vr = ka[q], vi = kb[q];
        if (q == 0) { vr += bias[da]; vi += bias[db]; }
        fwd8_first(L, q, (v2f){vr, vi},
                   (v2f){ka[q + 2048], kb[q + 2048]},
                   (v2f){ka[q + 4096], kb[q + 4096]},
                   (v2f){ka[q + 6144], kb[q + 6144]});
    }
    fwd8_stage<8>(L, t);   // S=256
    fwd8_stage<5>(L, t);   // S=32
    fwd8_stage<2>(L, t);   // S=4
    __syncthreads();
#pragma unroll 1
    for (int ch = 0; ch < 2; ++ch) {
        int n0 = (t << 4) + (ch << 3);
        v2f z0 = L[swz(n0)],     z1 = L[swz(n0 + 1)];
        v2f z2 = L[swz(n0 + 2)], z3 = L[swz(n0 + 3)];
        v2f z4 = L[swz(n0 + 4)], z5 = L[swz(n0 + 5)];
        v2f z6 = L[swz(n0 + 6)], z7 = L[swz(n0 + 7)];
        bf4f0(z0, z1, z2, z3); bf4f0(z4, z5, z6, z7);
        L[swz(n0)]     = z0; L[swz(n0 + 1)] = z1;
        L[swz(n0 + 2)] = z2; L[swz(n0 + 3)] = z3;
        L[swz(n0 + 4)] = z4; L[swz(n0 + 5)] = z5;
        L[swz(n0 + 6)] = z6; L[swz(n0 + 7)] = z7;
    }
    // Hermitian unpack + half2 store (1/N folded here, the ONLY scaling)
    __syncthreads();
    const float hn = 0.5f / 16384.f;
#pragma unroll 1
    for (int i = 0; i < 16; ++i) {
        int s = (i << 10) + t;
        int D0 = s >> 11, D1 = (s >> 8) & 7, D2 = (s >> 5) & 7, D3 = (s >> 2) & 7, E = s & 3;
        int n  = D0 + (D1 << 3) + (D2 << 6) + (D3 << 9) + (E << 12);
        int np = (16384 - n) & 16383;
        int sp = ((np & 7) << 11) | (((np >> 3) & 7) << 8) | (((np >> 6) & 7) << 5)
               | (((np >> 9) & 7) << 2) | ((np >> 12) & 3);
        v2f Zs = L[swz(s)];
        v2f Zp = L[swz(sp)];
        float kar = (Zs.x + Zp.x) * hn, kai = (Zs.y - Zp.y) * hn;
        float kbr = (Zs.y + Zp.y) * hn, kbi = (Zp.x - Zs.x) * hn;
        if (MODE == 0) {
            KF[(size_t)da * NF + s] = __floats2half2_rn(kar, kai);
            KF[(size_t)db * NF + s] = __floats2half2_rn(kbr, kbi);
        } else {
            __half2* Ha = (s < 8192)
                ? (__half2*)(outbase + (size_t)da * LSEQ) + s
                : (__half2*)(outbase + (size_t)(DIMC + da) * LSEQ) + (s - 8192);
            __half2* Hb = (s < 8192)
                ? (__half2*)(outbase + (size_t)db * LSEQ) + s
                : (__half2*)(outbase + (size_t)(DIMC + db) * LSEQ) + (s - 8192);
            *Ha = __floats2half2_rn(kar, kai);
            *Hb = __floats2half2_rn(kbr, kbi);
        }
    }
}

// ---------- Kernel 4: conv — fwd FFT(x packed), K-mult, inv FFT -----------
template<int MODE>
__global__ __launch_bounds__(1024)
void conv_kernel(const float* __restrict__ x, const __half2* __restrict__ KF,
                 float* __restrict__ out)
{
    __shared__ v2f L[NF];
    const int d = blockIdx.x, t = threadIdx.x;
    const float* x0 = x + (size_t)d * LSEQ;
    const float* x1 = x + (size_t)(DIMC + d) * LSEQ;
    float* o0 = out + (size_t)d * LSEQ;
    float* o1 = out + (size_t)(DIMC + d) * LSEQ;
#pragma unroll 1
    for (int m = 0; m < 2; ++m) {
        int q = t + (m << 10);
        fwd8_first(L, q, (v2f){x0[q], x1[q]},
                   (v2f){x0[q + 2048], x1[q + 2048]},
                   (v2f){x0[q + 4096], x1[q + 4096]},
                   (v2f){x0[q + 6144], x1[q + 6144]});
    }
    fwd8_stage<8>(L, t);
    fwd8_stage<5>(L, t);
    fwd8_stage<2>(L, t);
    // fwd r4 S=1 + K-mult (half2) + inv r4 S=1
    __syncthreads();
#pragma unroll 1
    for (int ch = 0; ch < 2; ++ch) {
        int n0 = (t << 4) + (ch << 3);
        v2f z0 = L[swz(n0)],     z1 = L[swz(n0 + 1)];
        v2f z2 = L[swz(n0 + 2)], z3 = L[swz(n0 + 3)];
        v2f z4 = L[swz(n0 + 4)], z5 = L[swz(n0 + 5)];
        v2f z6 = L[swz(n0 + 6)], z7 = L[swz(n0 + 7)];
        bf4f0(z0, z1, z2, z3); bf4f0(z4, z5, z6, z7);
        const __half2* H;
        if (MODE == 0) H = KF + (size_t)d * NF + n0;
        else H = (n0 < 8192)
            ? (const __half2*)(out + (size_t)d * LSEQ) + n0
            : (const __half2*)(out + (size_t)(DIMC + d) * LSEQ) + (n0 - 8192);
        // z*k = k*z.x + (i*k)*z.y
#define KMH(Z, J) { float2 kk = __half22float2(H[J]); v2f k = {kk.x, kk.y}; \
    Z = k * Z.x + pli(k) * Z.y; }
        KMH(z0,0) KMH(z1,1) KMH(z2,2) KMH(z3,3) KMH(z4,4) KMH(z5,5) KMH(z6,6) KMH(z7,7)
#undef KMH
        bf4i0(z0, z1, z2, z3); bf4i0(z4, z5, z6, z7);
        L[swz(n0)]     = z0; L[swz(n0 + 1)] = z1;
        L[swz(n0 + 2)] = z2; L[swz(n0 + 3)] = z3;
        L[swz(n0 + 4)] = z4; L[swz(n0 + 5)] = z5;
        L[swz(n0 + 6)] = z6; L[swz(n0 + 7)] = z7;
    }
    inv8_stage<2>(L, t);
    inv8_stage<5>(L, t);
    inv8_stage<8>(L, t);
    // inv radix-8 S=2048, truncated (outputs n<8192) + global store
    __syncthreads();
#pragma unroll 1
    for (int m = 0; m < 2; ++m) {
        int q = t + (m << 10);
        float th = (float)q * (PI_F / 8192.0f);
        TWCHAIN7(th);
        v2f y0 = L[swz(q)];
        v2f y1 = cmulp(L[swz(q + 2048)],  c1, s1);
        v2f y2 = cmulp(L[swz(q + 4096)],  c2, s2);
        v2f y3 = cmulp(L[swz(q + 6144)],  c3, s3);
        v2f y4 = cmulp(L[swz(q + 8192)],  c4, s4);
        v2f y5 = cmulp(L[swz(q + 10240)], c5, s5);
        v2f y6 = cmulp(L[swz(q + 12288)], c6, s6);
        v2f y7 = cmulp(L[swz(q + 14336)], c7, s7);
        v2f E0 = y0 + y4, F0 = y0 - y4;
        v2f E1 = y2 + y6, F1 = pli(y2 - y6);
        v2f a0 = E0 + E1, a2 = E0 - E1;
        v2f a1 = F0 + F1, a3 = F0 - F1;
        v2f G0 = y1 + y5, H0 = y1 - y5;
        v2f G1 = y3 + y7, H1 = pli(y3 - y7);
        v2f w0 = G0 + G1, w2 = G0 - G1;
        v2f w1 = H0 + H1, w3 = H0 - H1;
        v2f b0 = w0;
        v2f b1 = cmulp(w1,  RSQ2, RSQ2);
        v2f b2 = pli(w2);
        v2f b3 = cmulp(w3, -RSQ2, RSQ2);
        v2f r0 = a0 + b0, r1 = a1 + b1, r2 = a2 + b2, r3 = a3 + b3;
        o0[q]        = r0.x;  o1[q]        = r0.y;
        o0[q + 2048] = r1.x;  o1[q + 2048] = r1.y;
        o0[q + 4096] = r2.x;  o1[q + 4096] = r2.y;
        o0[q + 6144] = r3.x;  o1[q + 6144] = r3.y;
    }
}

extern "C" void kernel_launch(void* const* d_in, const int* in_sizes, int n_in,
                              void* d_out, int out_size, void* d_ws, size_t ws_size,
                              hipStream_t stream)
{
    (void)in_sizes; (void)n_in; (void)out_size;
    const float* x    = (const float*)d_in[0];
    const float* W0   = (const float*)d_in[1];
    const float* b0   = (const float*)d_in[2];
    const float* W1   = (const float*)d_in[3];
    const float* b1   = (const float*)d_in[4];
    const float* W2   = (const float*)d_in[5];
    const float* b2   = (const float*)d_in[6];
    const float* Wf   = (const float*)d_in[7];
    const float* freq = (const float*)d_in[8];
    const float* bias = (const float*)d_in[9];
    float* out = (float*)d_out;

    float* hws = out;                            // h2 staged in out rows 0..63
    float* kws = out + (size_t)DIMC * LSEQ;      // k staged in out rows 768..1535

    hipLaunchKernelGGL(hidden_kernel, dim3(LSEQ / 4), dim3(256), 0, stream,
                       W0, b0, W1, b1, W2, b2, freq, hws);
    hipLaunchKernelGGL(filter_kernel, dim3(LSEQ / 256, DIMC / DCHUNK), dim3(256), 0, stream,
                       hws, Wf, kws);

    const size_t kbytes = (size_t)DIMC * NF * sizeof(__half2);   // 50 MB
    if (ws_size >= kbytes) {
        __half2* KF = (__half2*)d_ws;
        hipLaunchKernelGGL(kfft_kernel<0>, dim3(DIMC / 2), dim3(1024), 0, stream,
                           kws, bias, KF, nullptr);
        hipLaunchKernelGGL(conv_kernel<0>, dim3(DIMC), dim3(1024), 0, stream,
                           x, KF, out);
    } else {
        hipLaunchKernelGGL(kfft_kernel<1>, dim3(DIMC / 2), dim3(1024), 0, stream,
                           kws, bias, nullptr, out);
        hipLaunchKernelGGL(conv_kernel<1>, dim3(DIMC), dim3(1024), 0, stream,
                           x, nullptr, out);
    }
}